// Round 3
// baseline (145.645 us; speedup 1.0000x reference)
//
#include <hip/hip_runtime.h>
#include <stdint.h>

typedef unsigned short u16;
typedef __attribute__((ext_vector_type(4))) float f32x4;
typedef __attribute__((ext_vector_type(8))) short bf16x8;
typedef __attribute__((ext_vector_type(4))) unsigned short u16x4;

#define DEV static __device__ __forceinline__

DEV u16 f2bf(float f) {
  union { float f; uint32_t u; } v; v.f = f;
  uint32_t u = v.u;
  return (u16)((u + 0x7FFFu + ((u >> 16) & 1u)) >> 16);
}

DEV float bf2f(u16 u) {
  union { uint32_t u; float f; } v; v.u = ((uint32_t)u) << 16;
  return v.f;
}

// ---------------- combined pre: pf-copy + x-cast + weight prep ----------------
// blocks [0,4096):        x -> pf (fp32) + x_bf (bf16), 8 elems/thread
// blocks [4096,4352):     transpose W1t [4096][256] -> W1T [256][4096]
// blocks [4352,4368):     transpose W2i [256][256]  -> W2iT
// blocks [4368,5136):     WcatT col n
// blocks [5136,5139):     biascat
__global__ __launch_bounds__(256) void k_pre(const float* __restrict__ x,
                                             float* __restrict__ pf,
                                             u16* __restrict__ xb,
                                             const float* __restrict__ W1t,
                                             const float* __restrict__ W2t,
                                             const float* __restrict__ W1i,
                                             const float* __restrict__ W2i,
                                             const float* __restrict__ b2t,
                                             const float* __restrict__ b1i,
                                             u16* __restrict__ W1T,
                                             u16* __restrict__ W2iT,
                                             u16* __restrict__ WcatT,
                                             float* __restrict__ biascat) {
  __shared__ u16 tile[64][65];
  __shared__ float col[256];
  int b = blockIdx.x;
  int t = threadIdx.x;
  if (b < 4096) {
    int i = b * 256 + t;
    #pragma unroll
    for (int h = 0; h < 2; ++h) {
      f32x4 v = *(const f32x4*)(x + i * 8 + h * 4);
      *(f32x4*)(pf + i * 8 + h * 4) = v;
      u16x4 o;
      #pragma unroll
      for (int e = 0; e < 4; ++e) o[e] = f2bf(v[e]);
      *(u16x4*)(xb + i * 8 + h * 4) = o;
    }
    return;
  }
  b -= 4096;
  if (b < 272) {
    const float* in;
    u16* out;
    int R, C, bb;
    if (b < 256) { in = W1t; out = W1T; R = 4096; C = 256; bb = b; }
    else         { in = W2i; out = W2iT; R = 256;  C = 256; bb = b - 256; }
    int tr = (bb >> 2) * 64, tc = (bb & 3) * 64;
    int lr = t & 63;
    #pragma unroll
    for (int it = 0; it < 16; ++it) {
      int r = it * 4 + (t >> 6);
      tile[r][lr] = f2bf(in[(tr + r) * C + tc + lr]);
    }
    __syncthreads();
    #pragma unroll
    for (int it = 0; it < 16; ++it) {
      int c = it * 4 + (t >> 6);
      out[(tc + c) * R + tr + lr] = tile[lr][c];
    }
    return;
  }
  if (b < 1040) {
    // WcatT [768][256] (k-contiguous):
    //   n<256: W2t[k][n]; n in [256,512): (W2t@W1i_top)[k][n-256]; else bottom half
    int n = b - 272;
    int k = t;
    if (n < 256) {
      WcatT[n * 256 + k] = f2bf(W2t[k * 256 + n]);
      return;
    }
    int off = (n < 512) ? 0 : 256;
    int c = n & 255;
    col[k] = W1i[(off + k) * 256 + c];
    __syncthreads();
    const float* wrow = W2t + k * 256;
    float acc = 0.f;
    #pragma unroll 4
    for (int m = 0; m < 256; ++m) acc += wrow[m] * col[m];
    WcatT[n * 256 + k] = f2bf(acc);
    return;
  }
  // biascat[768]: [b2_t | b2_t@W1i_top | b2_t@W1i_bot + b1_i]
  int n = (b - 1040) * 256 + t;
  float v;
  if (n < 256) {
    v = b2t[n];
  } else {
    int off = (n < 512) ? 0 : 256;
    int c = n & 255;
    float acc = (n < 512) ? 0.f : b1i[c];
    for (int k = 0; k < 256; ++k) acc += b2t[k] * W1i[(off + k) * 256 + c];
    v = acc;
  }
  biascat[n] = v;
}

// ---------------- GEMM1: x_bf[2048][4096] @ W1T[256][4096]^T, split-K=16 ----------------
// grid (64 m, 16 k), 256 thr = 4 waves (1m x 4n), wave tile 32 rows x 64 cols
// 1024 blocks -> 4 blocks/CU -> 4 waves/SIMD for L2-latency hiding.
// Partials stored bf16 (16 x 1 MB).
__global__ __launch_bounds__(256) void k_gemm1(const u16* __restrict__ A,
                                               const u16* __restrict__ BT,
                                               u16* __restrict__ part) {
  int w = threadIdx.x >> 6, l = threadIdx.x & 63;
  int m0 = blockIdx.x * 32;
  int n0 = w * 64;
  int k0 = blockIdx.y * 256 + ((l >> 4) * 8);
  const u16* pa0 = A + (m0 + (l & 15)) * 4096 + k0;
  const u16* pb0 = BT + (n0 + (l & 15)) * 4096 + k0;
  f32x4 acc[2][4] = {};
  #pragma unroll 2
  for (int ks = 0; ks < 8; ++ks) {
    bf16x8 a[2], bfr[4];
    #pragma unroll
    for (int mf = 0; mf < 2; ++mf)
      a[mf] = *(const bf16x8*)(pa0 + mf * 16 * 4096 + ks * 32);
    #pragma unroll
    for (int nf = 0; nf < 4; ++nf)
      bfr[nf] = *(const bf16x8*)(pb0 + nf * 16 * 4096 + ks * 32);
    #pragma unroll
    for (int mf = 0; mf < 2; ++mf)
      #pragma unroll
      for (int nf = 0; nf < 4; ++nf)
        acc[mf][nf] = __builtin_amdgcn_mfma_f32_16x16x32_bf16(bfr[nf], a[mf], acc[mf][nf], 0, 0, 0);
  }
  // swapped layout: M on (l&15), N on (l>>4)*4 + r -> 8B bf16x4 stores
  u16* out = part + blockIdx.y * (2048 * 256);
  #pragma unroll
  for (int mf = 0; mf < 2; ++mf) {
    int row = m0 + mf * 16 + (l & 15);
    #pragma unroll
    for (int nf = 0; nf < 4; ++nf) {
      int colv = n0 + nf * 16 + ((l >> 4) * 4);
      u16x4 o;
      #pragma unroll
      for (int r = 0; r < 4; ++r) o[r] = f2bf(acc[mf][nf][r]);
      *(u16x4*)(out + row * 256 + colv) = o;
    }
  }
}

// reduce 16 bf16 partials + b1_t, relu, -> h_bf bf16
__global__ __launch_bounds__(256) void k_reduce_h(const u16* __restrict__ part,
                                                  const float* __restrict__ b1t,
                                                  u16* __restrict__ hb) {
  int i = blockIdx.x * 256 + threadIdx.x;
  int e = i * 4;
  f32x4 s = {};
  #pragma unroll
  for (int z = 0; z < 16; ++z) {
    u16x4 p = *(const u16x4*)(part + z * (2048 * 256) + e);
    #pragma unroll
    for (int r = 0; r < 4; ++r) s[r] += bf2f(p[r]);
  }
  f32x4 bb = *(const f32x4*)(b1t + (e & 255));
  u16x4 o;
  #pragma unroll
  for (int r = 0; r < 4; ++r) o[r] = f2bf(fmaxf(s[r] + bb[r], 0.f));
  *(u16x4*)(hb + e) = o;
}

// ---------------- GEMM3: h_bf[2048][256] @ WcatT[768][256]^T ----------------
// grid (32 m, 12 n), 256 thr = 4 waves, wave 16 rows x 64 cols; swapped-store
__global__ __launch_bounds__(256) void k_gemm3(const u16* __restrict__ A,
                                               const u16* __restrict__ BT,
                                               const float* __restrict__ biascat,
                                               float* __restrict__ person,
                                               float* __restrict__ Apr,
                                               float* __restrict__ Bpr) {
  int w = threadIdx.x >> 6, l = threadIdx.x & 63;
  int row = blockIdx.x * 64 + w * 16 + (l & 15);
  int coln = blockIdx.y * 64;
  int k0 = (l >> 4) * 8;
  const u16* pa = A + row * 256 + k0;
  const u16* pb0 = BT + (coln + (l & 15)) * 256 + k0;
  f32x4 acc[4] = {};
  #pragma unroll
  for (int ks = 0; ks < 8; ++ks) {
    bf16x8 a = *(const bf16x8*)(pa + ks * 32);
    #pragma unroll
    for (int nf = 0; nf < 4; ++nf) {
      bf16x8 b = *(const bf16x8*)(pb0 + nf * 16 * 256 + ks * 32);
      acc[nf] = __builtin_amdgcn_mfma_f32_16x16x32_bf16(b, a, acc[nf], 0, 0, 0);
    }
  }
  float* dst;
  int cbase = coln;
  if (coln < 256) { dst = person; }
  else if (coln < 512) { dst = Apr; cbase = coln - 256; }
  else { dst = Bpr; cbase = coln - 512; }
  #pragma unroll
  for (int nf = 0; nf < 4; ++nf) {
    int lc = nf * 16 + ((l >> 4) * 4);
    f32x4 bias4 = *(const f32x4*)(biascat + coln + lc);
    *(f32x4*)(dst + row * 256 + cbase + lc) = acc[nf] + bias4;
  }
}

// ---------------- pair GEMM: relu(A'[i]+B'[j]) @ W2iT, swapped-store ----------------
// grid 1008 blocks x 512 thr (8 waves, 2x4), tile 128 rows x 256 cols, K=256
__global__ __launch_bounds__(512, 2) void k_pair_gemm(const float* __restrict__ Apr,
                                                      const float* __restrict__ Bpr,
                                                      const u16* __restrict__ W2iT,
                                                      const float* __restrict__ b2i,
                                                      float* __restrict__ rel) {
  __shared__ u16 hi[128 * 264];  // pitch 264 u16: 16B-aligned rows
  int t = threadIdx.x;
  int lane = t & 63;
  int R0 = blockIdx.x * 128;
  // phase 1: compute hi tile (bf16) into LDS
  #pragma unroll
  for (int it = 0; it < 16; ++it) {
    int r = it * 8 + (t >> 6);
    int R = R0 + r;
    int b = R / 4032;
    int q = R - b * 4032;
    int i = q / 63;
    int rem = q - i * 63;
    int j = rem + (rem >= i ? 1 : 0);
    f32x4 va = *(const f32x4*)(Apr + (b * 64 + i) * 256 + lane * 4);
    f32x4 vb = *(const f32x4*)(Bpr + (b * 64 + j) * 256 + lane * 4);
    u16x4 o;
    #pragma unroll
    for (int e = 0; e < 4; ++e) o[e] = f2bf(fmaxf(va[e] + vb[e], 0.f));
    *(u16x4*)(&hi[r * 264 + lane * 4]) = o;
  }
  __syncthreads();
  // phase 2: barrier-free MFMA K-loop; B-frags streamed from L2-hot W2iT
  int wid = t >> 6;
  int wr = wid >> 2, wc = wid & 3;  // 2 x 4 waves, each 64x64
  f32x4 acc[4][4] = {};
  int arow0 = wr * 64 + (lane & 15);
  int koff = (lane >> 4) * 8;
  const u16* pb0 = W2iT + (wc * 64 + (lane & 15)) * 256 + koff;
  #pragma unroll 2
  for (int ks = 0; ks < 8; ++ks) {
    bf16x8 a[4], bfr[4];
    #pragma unroll
    for (int mf = 0; mf < 4; ++mf)
      a[mf] = *(const bf16x8*)(&hi[(arow0 + mf * 16) * 264 + ks * 32 + koff]);
    #pragma unroll
    for (int nf = 0; nf < 4; ++nf)
      bfr[nf] = *(const bf16x8*)(pb0 + nf * 16 * 256 + ks * 32);
    #pragma unroll
    for (int mf = 0; mf < 4; ++mf)
      #pragma unroll
      for (int nf = 0; nf < 4; ++nf)
        acc[mf][nf] = __builtin_amdgcn_mfma_f32_16x16x32_bf16(bfr[nf], a[mf], acc[mf][nf], 0, 0, 0);
  }
  // epilogue: swapped layout -> M on (l&15), N on (l>>4)*4+r; f32x4 stores
  f32x4 bias4[4];
  #pragma unroll
  for (int nf = 0; nf < 4; ++nf)
    bias4[nf] = *(const f32x4*)(b2i + wc * 64 + nf * 16 + ((lane >> 4) * 4));
  #pragma unroll
  for (int mf = 0; mf < 4; ++mf) {
    int row = R0 + wr * 64 + mf * 16 + (lane & 15);
    #pragma unroll
    for (int nf = 0; nf < 4; ++nf) {
      int gc = wc * 64 + nf * 16 + ((lane >> 4) * 4);
      *(f32x4*)(rel + row * 256 + gc) = acc[mf][nf] + bias4[nf];
    }
  }
}

// ---------------- launch ----------------

extern "C" void kernel_launch(void* const* d_in, const int* in_sizes, int n_in,
                              void* d_out, int out_size, void* d_ws, size_t ws_size,
                              hipStream_t stream) {
  const float* x   = (const float*)d_in[0];
  const float* W1t = (const float*)d_in[1];
  const float* b1t = (const float*)d_in[2];
  const float* W2t = (const float*)d_in[3];
  const float* b2t = (const float*)d_in[4];
  const float* W1i = (const float*)d_in[5];
  const float* b1i = (const float*)d_in[6];
  const float* W2i = (const float*)d_in[7];
  const float* b2i = (const float*)d_in[8];

  float* out = (float*)d_out;
  float* rel = out;                       // [32][4032][256]
  float* pf = out + 33030144;             // [32][64][16][256]
  float* person = out + 41418752;         // [32][64][256]

  char* ws = (char*)d_ws;
  u16*   x_bf    = (u16*)(ws + 0);          // 16,777,216 B
  u16*   W1T     = (u16*)(ws + 16777216);   //  2,097,152 B
  u16*   WcatT   = (u16*)(ws + 18874368);   //    393,216 B
  u16*   W2iT    = (u16*)(ws + 19267584);   //    131,072 B
  float* biascat = (float*)(ws + 19398656); //      4,096 B
  u16*   h_bf    = (u16*)(ws + 19402752);   //  1,048,576 B
  float* Apr     = (float*)(ws + 20451328); //  2,097,152 B
  float* Bpr     = (float*)(ws + 22548480); //  2,097,152 B
  u16*   part    = (u16*)(ws + 24645632);   // 16,777,216 B (16 x 1MB bf16)

  k_pre<<<5139, 256, 0, stream>>>(x, pf, x_bf, W1t, W2t, W1i, W2i, b2t, b1i,
                                  W1T, W2iT, WcatT, biascat);
  k_gemm1<<<dim3(64, 16), 256, 0, stream>>>(x_bf, W1T, part);
  k_reduce_h<<<512, 256, 0, stream>>>(part, b1t, h_bf);
  k_gemm3<<<dim3(32, 12), 256, 0, stream>>>(h_bf, WcatT, biascat, person, Apr, Bpr);
  k_pair_gemm<<<1008, 512, 0, stream>>>(Apr, Bpr, W2iT, b2i, rel);
}

// Round 4
// 119.621 us; speedup vs baseline: 1.2176x; 1.2176x over previous
//
#include <hip/hip_runtime.h>
#include <stdint.h>

typedef unsigned short u16;
typedef __attribute__((ext_vector_type(4))) float f32x4;
typedef __attribute__((ext_vector_type(8))) short bf16x8;
typedef __attribute__((ext_vector_type(4))) unsigned short u16x4;

#define DEV static __device__ __forceinline__

DEV u16 f2bf(float f) {
  union { float f; uint32_t u; } v; v.f = f;
  uint32_t u = v.u;
  return (u16)((u + 0x7FFFu + ((u >> 16) & 1u)) >> 16);
}

DEV float bf2f(u16 u) {
  union { uint32_t u; float f; } v; v.u = ((uint32_t)u) << 16;
  return v.f;
}

// ---------------- weight prep ----------------
// blocks [0,256):    transpose W1t [4096][256] -> W1T [256][4096]
// blocks [256,272):  transpose W2i [256][256]  -> W2iT
// blocks [272,1040): WcatT col n
// blocks [1040,1043): biascat
__global__ __launch_bounds__(256) void k_prep(const float* __restrict__ W1t,
                                              const float* __restrict__ W2t,
                                              const float* __restrict__ W1i,
                                              const float* __restrict__ W2i,
                                              const float* __restrict__ b2t,
                                              const float* __restrict__ b1i,
                                              u16* __restrict__ W1T,
                                              u16* __restrict__ W2iT,
                                              u16* __restrict__ WcatT,
                                              float* __restrict__ biascat) {
  __shared__ u16 tile[64][65];
  __shared__ float col[256];
  int b = blockIdx.x;
  int t = threadIdx.x;
  if (b < 272) {
    const float* in;
    u16* out;
    int R, C, bb;
    if (b < 256) { in = W1t; out = W1T; R = 4096; C = 256; bb = b; }
    else         { in = W2i; out = W2iT; R = 256;  C = 256; bb = b - 256; }
    int tr = (bb >> 2) * 64, tc = (bb & 3) * 64;
    int lr = t & 63;
    #pragma unroll
    for (int it = 0; it < 16; ++it) {
      int r = it * 4 + (t >> 6);
      tile[r][lr] = f2bf(in[(tr + r) * C + tc + lr]);
    }
    __syncthreads();
    #pragma unroll
    for (int it = 0; it < 16; ++it) {
      int c = it * 4 + (t >> 6);
      out[(tc + c) * R + tr + lr] = tile[lr][c];
    }
    return;
  }
  if (b < 1040) {
    // WcatT [768][256] (k-contiguous)
    int n = b - 272;
    int k = t;
    if (n < 256) {
      WcatT[n * 256 + k] = f2bf(W2t[k * 256 + n]);
      return;
    }
    int off = (n < 512) ? 0 : 256;
    int c = n & 255;
    col[k] = W1i[(off + k) * 256 + c];
    __syncthreads();
    const float* wrow = W2t + k * 256;
    float acc = 0.f;
    #pragma unroll 4
    for (int m = 0; m < 256; ++m) acc += wrow[m] * col[m];
    WcatT[n * 256 + k] = f2bf(acc);
    return;
  }
  // biascat[768]: [b2_t | b2_t@W1i_top | b2_t@W1i_bot + b1_i]
  int n = (b - 1040) * 256 + t;
  float v;
  if (n < 256) {
    v = b2t[n];
  } else {
    int off = (n < 512) ? 0 : 256;
    int c = n & 255;
    float acc = (n < 512) ? 0.f : b1i[c];
    for (int k = 0; k < 256; ++k) acc += b2t[k] * W1i[(off + k) * 256 + c];
    v = acc;
  }
  biascat[n] = v;
}

// ---------------- GEMM1 fused: x fp32 -> pf copy + bf16 LDS tile -> MFMA ----------------
// grid (64 m, 8 kz), 256 thr = 4 waves (1m x 4n). Block tile: 32 rows x 256 N, K=512.
// Each block owns x rows [32bx,32bx+32) x cols [512kz,512kz+512) exclusively:
// loads fp32 once, writes pf, stages bf16 in LDS, MFMAs vs L2-hot W1T.
__global__ __launch_bounds__(256) void k_gemm1f(const float* __restrict__ x,
                                                float* __restrict__ pf,
                                                const u16* __restrict__ BT,
                                                u16* __restrict__ part) {
  __shared__ u16 As[32][520];  // pitch 520 u16 = 260 dw -> 4-bank row stride
  int t = threadIdx.x;
  int m0 = blockIdx.x * 32;
  int k0 = blockIdx.y * 512;
  // stage phase: 32x512 fp32 (64 KB), 64 floats/thread
  {
    int row = t >> 3;
    int cb = (t & 7) * 4;
    const float* src = x + (m0 + row) * 4096 + k0;
    float* dst = pf + (m0 + row) * 4096 + k0;
    #pragma unroll
    for (int j = 0; j < 16; ++j) {
      f32x4 v = *(const f32x4*)(src + cb + j * 32);
      *(f32x4*)(dst + cb + j * 32) = v;
      u16x4 o;
      #pragma unroll
      for (int e = 0; e < 4; ++e) o[e] = f2bf(v[e]);
      *(u16x4*)(&As[row][cb + j * 32]) = o;
    }
  }
  __syncthreads();
  // MFMA phase
  int w = t >> 6, l = t & 63;
  int n0 = w * 64;
  int koff = (l >> 4) * 8;
  const u16* pb0 = BT + (n0 + (l & 15)) * 4096 + k0 + koff;
  int ar = l & 15;
  f32x4 acc[2][4] = {};
  for (int ks = 0; ks < 16; ++ks) {
    bf16x8 a[2], bfr[4];
    #pragma unroll
    for (int mf = 0; mf < 2; ++mf)
      a[mf] = *(const bf16x8*)(&As[ar + mf * 16][koff + ks * 32]);
    #pragma unroll
    for (int nf = 0; nf < 4; ++nf)
      bfr[nf] = *(const bf16x8*)(pb0 + nf * 16 * 4096 + ks * 32);
    #pragma unroll
    for (int mf = 0; mf < 2; ++mf)
      #pragma unroll
      for (int nf = 0; nf < 4; ++nf)
        acc[mf][nf] = __builtin_amdgcn_mfma_f32_16x16x32_bf16(bfr[nf], a[mf], acc[mf][nf], 0, 0, 0);
  }
  // swapped layout: M on (l&15), N on (l>>4)*4 + r -> 8B bf16x4 stores
  u16* out = part + blockIdx.y * (2048 * 256);
  #pragma unroll
  for (int mf = 0; mf < 2; ++mf) {
    int row = m0 + mf * 16 + (l & 15);
    #pragma unroll
    for (int nf = 0; nf < 4; ++nf) {
      int colv = n0 + nf * 16 + ((l >> 4) * 4);
      u16x4 o;
      #pragma unroll
      for (int r = 0; r < 4; ++r) o[r] = f2bf(acc[mf][nf][r]);
      *(u16x4*)(out + row * 256 + colv) = o;
    }
  }
}

// reduce 8 bf16 partials + b1_t, relu, -> h_bf bf16
__global__ __launch_bounds__(256) void k_reduce_h(const u16* __restrict__ part,
                                                  const float* __restrict__ b1t,
                                                  u16* __restrict__ hb) {
  int i = blockIdx.x * 256 + threadIdx.x;
  int e = i * 4;
  f32x4 s = {};
  #pragma unroll
  for (int z = 0; z < 8; ++z) {
    u16x4 p = *(const u16x4*)(part + z * (2048 * 256) + e);
    #pragma unroll
    for (int r = 0; r < 4; ++r) s[r] += bf2f(p[r]);
  }
  f32x4 bb = *(const f32x4*)(b1t + (e & 255));
  u16x4 o;
  #pragma unroll
  for (int r = 0; r < 4; ++r) o[r] = f2bf(fmaxf(s[r] + bb[r], 0.f));
  *(u16x4*)(hb + e) = o;
}

// ---------------- GEMM3: h_bf[2048][256] @ WcatT[768][256]^T ----------------
__global__ __launch_bounds__(256) void k_gemm3(const u16* __restrict__ A,
                                               const u16* __restrict__ BT,
                                               const float* __restrict__ biascat,
                                               float* __restrict__ person,
                                               float* __restrict__ Apr,
                                               float* __restrict__ Bpr) {
  int w = threadIdx.x >> 6, l = threadIdx.x & 63;
  int row = blockIdx.x * 64 + w * 16 + (l & 15);
  int coln = blockIdx.y * 64;
  int k0 = (l >> 4) * 8;
  const u16* pa = A + row * 256 + k0;
  const u16* pb0 = BT + (coln + (l & 15)) * 256 + k0;
  f32x4 acc[4] = {};
  #pragma unroll
  for (int ks = 0; ks < 8; ++ks) {
    bf16x8 a = *(const bf16x8*)(pa + ks * 32);
    #pragma unroll
    for (int nf = 0; nf < 4; ++nf) {
      bf16x8 b = *(const bf16x8*)(pb0 + nf * 16 * 256 + ks * 32);
      acc[nf] = __builtin_amdgcn_mfma_f32_16x16x32_bf16(b, a, acc[nf], 0, 0, 0);
    }
  }
  float* dst;
  int cbase = coln;
  if (coln < 256) { dst = person; }
  else if (coln < 512) { dst = Apr; cbase = coln - 256; }
  else { dst = Bpr; cbase = coln - 512; }
  #pragma unroll
  for (int nf = 0; nf < 4; ++nf) {
    int lc = nf * 16 + ((l >> 4) * 4);
    f32x4 bias4 = *(const f32x4*)(biascat + coln + lc);
    *(f32x4*)(dst + row * 256 + cbase + lc) = acc[nf] + bias4;
  }
}

// ---------------- pair GEMM: relu(A'[i]+B'[j]) @ W2iT, swapped-store ----------------
__global__ __launch_bounds__(512, 2) void k_pair_gemm(const float* __restrict__ Apr,
                                                      const float* __restrict__ Bpr,
                                                      const u16* __restrict__ W2iT,
                                                      const float* __restrict__ b2i,
                                                      float* __restrict__ rel) {
  __shared__ u16 hi[128 * 264];
  int t = threadIdx.x;
  int lane = t & 63;
  int R0 = blockIdx.x * 128;
  #pragma unroll
  for (int it = 0; it < 16; ++it) {
    int r = it * 8 + (t >> 6);
    int R = R0 + r;
    int b = R / 4032;
    int q = R - b * 4032;
    int i = q / 63;
    int rem = q - i * 63;
    int j = rem + (rem >= i ? 1 : 0);
    f32x4 va = *(const f32x4*)(Apr + (b * 64 + i) * 256 + lane * 4);
    f32x4 vb = *(const f32x4*)(Bpr + (b * 64 + j) * 256 + lane * 4);
    u16x4 o;
    #pragma unroll
    for (int e = 0; e < 4; ++e) o[e] = f2bf(fmaxf(va[e] + vb[e], 0.f));
    *(u16x4*)(&hi[r * 264 + lane * 4]) = o;
  }
  __syncthreads();
  int wid = t >> 6;
  int wr = wid >> 2, wc = wid & 3;  // 2 x 4 waves, each 64x64
  f32x4 acc[4][4] = {};
  int arow0 = wr * 64 + (lane & 15);
  int koff = (lane >> 4) * 8;
  const u16* pb0 = W2iT + (wc * 64 + (lane & 15)) * 256 + koff;
  #pragma unroll 2
  for (int ks = 0; ks < 8; ++ks) {
    bf16x8 a[4], bfr[4];
    #pragma unroll
    for (int mf = 0; mf < 4; ++mf)
      a[mf] = *(const bf16x8*)(&hi[(arow0 + mf * 16) * 264 + ks * 32 + koff]);
    #pragma unroll
    for (int nf = 0; nf < 4; ++nf)
      bfr[nf] = *(const bf16x8*)(pb0 + nf * 16 * 256 + ks * 32);
    #pragma unroll
    for (int mf = 0; mf < 4; ++mf)
      #pragma unroll
      for (int nf = 0; nf < 4; ++nf)
        acc[mf][nf] = __builtin_amdgcn_mfma_f32_16x16x32_bf16(bfr[nf], a[mf], acc[mf][nf], 0, 0, 0);
  }
  f32x4 bias4[4];
  #pragma unroll
  for (int nf = 0; nf < 4; ++nf)
    bias4[nf] = *(const f32x4*)(b2i + wc * 64 + nf * 16 + ((lane >> 4) * 4));
  #pragma unroll
  for (int mf = 0; mf < 4; ++mf) {
    int row = R0 + wr * 64 + mf * 16 + (lane & 15);
    #pragma unroll
    for (int nf = 0; nf < 4; ++nf) {
      int gc = wc * 64 + nf * 16 + ((lane >> 4) * 4);
      *(f32x4*)(rel + row * 256 + gc) = acc[mf][nf] + bias4[nf];
    }
  }
}

// ---------------- launch ----------------

extern "C" void kernel_launch(void* const* d_in, const int* in_sizes, int n_in,
                              void* d_out, int out_size, void* d_ws, size_t ws_size,
                              hipStream_t stream) {
  const float* x   = (const float*)d_in[0];
  const float* W1t = (const float*)d_in[1];
  const float* b1t = (const float*)d_in[2];
  const float* W2t = (const float*)d_in[3];
  const float* b2t = (const float*)d_in[4];
  const float* W1i = (const float*)d_in[5];
  const float* b1i = (const float*)d_in[6];
  const float* W2i = (const float*)d_in[7];
  const float* b2i = (const float*)d_in[8];

  float* out = (float*)d_out;
  float* rel = out;                       // [32][4032][256]
  float* pf = out + 33030144;             // [32][64][16][256]
  float* person = out + 41418752;         // [32][64][256]

  char* ws = (char*)d_ws;
  u16*   W1T     = (u16*)(ws + 0);          //  2,097,152 B
  u16*   WcatT   = (u16*)(ws + 2097152);    //    393,216 B
  u16*   W2iT    = (u16*)(ws + 2490368);    //    131,072 B
  float* biascat = (float*)(ws + 2621440);  //      4,096 B
  u16*   h_bf    = (u16*)(ws + 2625536);    //  1,048,576 B
  float* Apr     = (float*)(ws + 3674112);  //  2,097,152 B
  float* Bpr     = (float*)(ws + 5771264);  //  2,097,152 B
  u16*   part    = (u16*)(ws + 7868416);    //  8,388,608 B (8 x 1MB bf16)

  k_prep<<<1043, 256, 0, stream>>>(W1t, W2t, W1i, W2i, b2t, b1i,
                                   W1T, W2iT, WcatT, biascat);
  k_gemm1f<<<dim3(64, 8), 256, 0, stream>>>(x, pf, W1T, part);
  k_reduce_h<<<512, 256, 0, stream>>>(part, b1t, h_bf);
  k_gemm3<<<dim3(32, 12), 256, 0, stream>>>(h_bf, WcatT, biascat, person, Apr, Bpr);
  k_pair_gemm<<<1008, 512, 0, stream>>>(Apr, Bpr, W2iT, b2i, rel);
}